// Round 4
// baseline (1269.773 us; speedup 1.0000x reference)
//
#include <hip/hip_runtime.h>
#include <hip/hip_bf16.h>
#include <stdint.h>
#include <stdio.h>

// Problem sizes (fixed by setup_inputs)
#define B_ 4
#define S_ 2048
#define D_ 2048
#define P_ 2729
#define NP 2816            // P padded to multiple of 256
#define M_ (B_ * S_)       // 8192

#define SCHUNK 128
#define NCHUNK (S_ / SCHUNK)   // 16

typedef __attribute__((ext_vector_type(8))) short bh8;   // 8 x bf16 (4 VGPRs)
typedef __attribute__((ext_vector_type(4))) float fx4;   // MFMA accumulator

static __device__ __forceinline__ float bf2f(unsigned short u) {
  union { unsigned int i; float f; } c;
  c.i = ((unsigned int)u) << 16;
  return c.f;
}
static __device__ __forceinline__ unsigned short f2bf(float f) {
  union { __hip_bfloat16 h; unsigned short u; } c;
  c.h = __float2bfloat16(f);
  return c.u;
}
static __device__ __forceinline__ float fast_tanh(float x) {
  return 1.0f - 2.0f / (__expf(2.0f * x) + 1.0f);
}
static __device__ __forceinline__ float gate_act(float z) {
  float sc = 15.0f * fast_tanh(z * (1.0f / 15.0f));
  return 1.0f / (1.0f + __expf(-sc));
}

static __device__ __forceinline__ void gload_lds16(const ushort* g, ushort* l) {
  __builtin_amdgcn_global_load_lds(
      (const __attribute__((address_space(1))) unsigned int*)g,
      (__attribute__((address_space(3))) unsigned int*)l, 16, 0, 0);
}

// ---------------- RMSNorm + bf16 cast ----------------
__global__ __launch_bounds__(256) void rmsnorm_kernel(const float* __restrict__ x,
                                                      const float* __restrict__ w,
                                                      __hip_bfloat16* __restrict__ xn) {
  int row = blockIdx.x;
  const float4* xr = (const float4*)(x + (size_t)row * D_);
  int t = threadIdx.x;
  float4 v0 = xr[t];
  float4 v1 = xr[t + 256];
  float ss = v0.x * v0.x + v0.y * v0.y + v0.z * v0.z + v0.w * v0.w +
             v1.x * v1.x + v1.y * v1.y + v1.z * v1.z + v1.w * v1.w;
#pragma unroll
  for (int off = 32; off > 0; off >>= 1) ss += __shfl_down(ss, off);
  __shared__ float red[4];
  if ((t & 63) == 0) red[t >> 6] = ss;
  __syncthreads();
  float scale = rsqrtf((red[0] + red[1] + red[2] + red[3]) * (1.0f / (float)D_) + 1e-6f);
  const float4* wp = (const float4*)w;
  float4 w0 = wp[t], w1 = wp[t + 256];
  ushort4 o0, o1;
  o0.x = f2bf(v0.x * scale * w0.x);
  o0.y = f2bf(v0.y * scale * w0.y);
  o0.z = f2bf(v0.z * scale * w0.z);
  o0.w = f2bf(v0.w * scale * w0.w);
  o1.x = f2bf(v1.x * scale * w1.x);
  o1.y = f2bf(v1.y * scale * w1.y);
  o1.z = f2bf(v1.z * scale * w1.z);
  o1.w = f2bf(v1.w * scale * w1.w);
  ushort4* xo = (ushort4*)(xn + (size_t)row * D_);
  xo[t] = o0;
  xo[t + 256] = o1;
}

// ---------------- weight conversion ----------------
__global__ __launch_bounds__(256) void convert_gate_w(const float* __restrict__ Wi,
                                                      const float* __restrict__ Wf,
                                                      const float* __restrict__ Wo,
                                                      const float* __restrict__ Wc,
                                                      __hip_bfloat16* __restrict__ Wb) {
  int g = blockIdx.z;
  const float* W = (g == 0) ? Wi : (g == 1) ? Wf : (g == 2) ? Wo : Wc;
  size_t u = (size_t)blockIdx.x * 256 + threadIdx.x;  // float4 index, NP*512 per gate
  int j = (int)(u >> 9);
  int q = (int)(u & 511);
  ushort4 o;
  if (j < P_) {
    float4 v = ((const float4*)(W + (size_t)j * D_))[q];
    o.x = f2bf(v.x); o.y = f2bf(v.y); o.z = f2bf(v.z); o.w = f2bf(v.w);
  } else {
    o.x = 0; o.y = 0; o.z = 0; o.w = 0;
  }
  ushort4* dst = (ushort4*)(Wb + (size_t)g * NP * D_ + (size_t)j * D_ + (size_t)q * 4);
  *dst = o;
}

__global__ __launch_bounds__(256) void convert_wout(const float* __restrict__ Wout,
                                                    __hip_bfloat16* __restrict__ Woutb) {
  size_t u = (size_t)blockIdx.x * 256 + threadIdx.x;
  if (u >= (size_t)D_ * NP) return;
  int d = (int)(u / NP);
  int p = (int)(u - (size_t)d * NP);
  float v = (p < P_) ? Wout[(size_t)d * P_ + p] : 0.0f;
  Woutb[u] = __float2bfloat16(v);
}

// ---------------- 256x256 8-phase GEMM core (C = A * B^T), bf16 ----------------
// 512 threads = 8 waves (2M x 4N); per-wave output 128x64.
// LDS: 8 half-tile slots of [128 rows][64 cols] bf16 (16 KB each) = 128 KiB:
//   R[0]=A.h0 buf0, R[1]=A.h1 buf0, R[2]=B.h0 buf0, R[3]=B.h1 buf0, R[4..7]=buf1.
// XOR-swizzled reads (byte ^= (row&7)<<4) + linear gload_lds dest with
// pre-swizzled global source (rule #21). Counted-vmcnt pipeline:
//   stage schedule (iter j: u=2j even->buf0, v=2j+1 odd->buf1):
//     ph1: A(v,h1)->R5   ph3: B(u+2,h0)->R2   ph4: B(u+2,h1)->R3 [gate vmcnt(4)]
//     ph5: A(u+2,h0/h1)->R0,R1   ph7: B(v+2,h0)->R6
//     ph8: B(v+2,h1)->R7 + A(v+2,h0)->R4 [gate vmcnt(6)]
//   Ledger: 14 loads issued = 14 drained per iter; at ph4 gate the oldest
//   needed (A(v,h1)@ph1) is 3 phases back; at ph8 (A(u+2)@ph5) 3 phases back.
//   Every slot restage is >=1 barrier after its last read's lgkm-forced
//   completion (reads complete before that phase's MFMA -> pre-post barrier).
#define MM8(MB, NB, BV)                                                                         \
  _Pragma("unroll") for (int mi = 0; mi < 4; ++mi)                                              \
  _Pragma("unroll") for (int ni = 0; ni < 2; ++ni) {                                            \
    acc[MB + mi][NB + ni] =                                                                     \
        __builtin_amdgcn_mfma_f32_16x16x32_bf16(af[mi][0], BV[ni][0], acc[MB + mi][NB + ni], 0, 0, 0); \
    acc[MB + mi][NB + ni] =                                                                     \
        __builtin_amdgcn_mfma_f32_16x16x32_bf16(af[mi][1], BV[ni][1], acc[MB + mi][NB + ni], 0, 0, 0); \
  }

template <int LD, int NKT>
static __device__ __forceinline__ void gemm256_core(const ushort* __restrict__ A,
                                                    const ushort* __restrict__ Bm,
                                                    int tile_m, int tile_n,
                                                    ushort* lds, fx4 (&acc)[8][4]) {
  const int t = threadIdx.x;
  const int lane = t & 63;
  const int w = t >> 6;
  const int wr = w >> 2;            // 0..1 (M half)
  const int wc = w & 3;             // 0..3 (N quarter)
  const int frow = lane & 15;
  const int g = lane >> 4;
  const int xr = (frow & 7) << 4;

  ushort* R[8];
#pragma unroll
  for (int i = 0; i < 8; ++i) R[i] = lds + i * 8192;

  // staging: q in {0,1}: LDS elems (q*512+t)*8 (linear); row r=(q*512+t)>>3;
  // source col pre-swizzled: ((t&7)^(r&7))*8  (r&7 identical for q=0,1)
  const int r0 = t >> 3;
  const int gc0 = ((t & 7) ^ (r0 & 7)) << 3;
  const ushort* baseA = A + (size_t)(tile_m + r0) * LD + gc0;
  const ushort* baseB = Bm + (size_t)(tile_n + r0) * LD + gc0;
  const size_t rstep = (size_t)64 * LD;

  auto STAGE = [&](const ushort* mb, int h, int kt, int slot) {
    const ushort* p = mb + (size_t)(h * 128) * LD + kt * 64;
    gload_lds16(p, R[slot] + t * 8);
    gload_lds16(p + rstep, R[slot] + 4096 + t * 8);
  };

  const char* bA[2] = { (const char*)R[wr] + (frow << 7),
                        (const char*)R[4 + wr] + (frow << 7) };
  const int brow = (((wc & 1) << 6) + frow) << 7;
  const char* bB[2] = { (const char*)R[2 + (wc >> 1)] + brow,
                        (const char*)R[6 + (wc >> 1)] + brow };
  const int c0 = (g << 4) ^ xr;
  const int c1 = (64 + (g << 4)) ^ xr;

  // prologue: tile0 (buf0) + A(1,h0) + B(1,h0/h1); drain tile0, keep 6 in flight
  STAGE(baseA, 0, 0, 0); STAGE(baseA, 1, 0, 1);
  STAGE(baseB, 0, 0, 2); STAGE(baseB, 1, 0, 3);
  STAGE(baseA, 0, 1, 4);
  STAGE(baseB, 0, 1, 6); STAGE(baseB, 1, 1, 7);
  asm volatile("s_waitcnt vmcnt(6)" ::: "memory");
  __builtin_amdgcn_s_barrier();

  bh8 af[4][2], b0[2][2], b1[2][2];

  for (int j = 0; j < NKT / 2; ++j) {
    const int v = 2 * j + 1;
    const bool more = (j + 1 < NKT / 2);

    // ---- ph1: Q00(u); stage A(v,h1) ----
#pragma unroll
    for (int mi = 0; mi < 4; ++mi) {
      af[mi][0] = *(const bh8*)(bA[0] + (mi << 11) + c0);
      af[mi][1] = *(const bh8*)(bA[0] + (mi << 11) + c1);
    }
#pragma unroll
    for (int ni = 0; ni < 2; ++ni) {
      b0[ni][0] = *(const bh8*)(bB[0] + (ni << 11) + c0);
      b0[ni][1] = *(const bh8*)(bB[0] + (ni << 11) + c1);
    }
    STAGE(baseA, 1, v, 5);
    __builtin_amdgcn_s_barrier();
    __builtin_amdgcn_s_setprio(1);
    MM8(0, 0, b0)
    __builtin_amdgcn_s_setprio(0);
    __builtin_amdgcn_s_barrier();

    // ---- ph2: Q01(u) ----
#pragma unroll
    for (int ni = 0; ni < 2; ++ni) {
      b1[ni][0] = *(const bh8*)(bB[0] + ((ni + 2) << 11) + c0);
      b1[ni][1] = *(const bh8*)(bB[0] + ((ni + 2) << 11) + c1);
    }
    __builtin_amdgcn_s_barrier();
    __builtin_amdgcn_s_setprio(1);
    MM8(0, 2, b1)
    __builtin_amdgcn_s_setprio(0);
    __builtin_amdgcn_s_barrier();

    // ---- ph3: Q11(u); stage B(u+2,h0) ----
#pragma unroll
    for (int mi = 0; mi < 4; ++mi) {
      af[mi][0] = *(const bh8*)(bA[0] + ((mi + 4) << 11) + c0);
      af[mi][1] = *(const bh8*)(bA[0] + ((mi + 4) << 11) + c1);
    }
    if (more) STAGE(baseB, 0, 2 * j + 2, 2);
    __builtin_amdgcn_s_barrier();
    __builtin_amdgcn_s_setprio(1);
    MM8(4, 2, b1)
    __builtin_amdgcn_s_setprio(0);
    __builtin_amdgcn_s_barrier();

    // ---- ph4: Q10(u); stage B(u+2,h1); GATE (buf1 must be complete) ----
    if (more) STAGE(baseB, 1, 2 * j + 2, 3);
    __builtin_amdgcn_s_barrier();
    __builtin_amdgcn_s_setprio(1);
    MM8(4, 0, b0)
    __builtin_amdgcn_s_setprio(0);
    if (more) { asm volatile("s_waitcnt vmcnt(4)" ::: "memory"); }
    else      { asm volatile("s_waitcnt vmcnt(0)" ::: "memory"); }
    __builtin_amdgcn_s_barrier();

    // ---- ph5: Q00(v); stage A(u+2,h0), A(u+2,h1) ----
#pragma unroll
    for (int mi = 0; mi < 4; ++mi) {
      af[mi][0] = *(const bh8*)(bA[1] + (mi << 11) + c0);
      af[mi][1] = *(const bh8*)(bA[1] + (mi << 11) + c1);
    }
#pragma unroll
    for (int ni = 0; ni < 2; ++ni) {
      b0[ni][0] = *(const bh8*)(bB[1] + (ni << 11) + c0);
      b0[ni][1] = *(const bh8*)(bB[1] + (ni << 11) + c1);
    }
    if (more) { STAGE(baseA, 0, 2 * j + 2, 0); STAGE(baseA, 1, 2 * j + 2, 1); }
    __builtin_amdgcn_s_barrier();
    __builtin_amdgcn_s_setprio(1);
    MM8(0, 0, b0)
    __builtin_amdgcn_s_setprio(0);
    __builtin_amdgcn_s_barrier();

    // ---- ph6: Q01(v) ----
#pragma unroll
    for (int ni = 0; ni < 2; ++ni) {
      b1[ni][0] = *(const bh8*)(bB[1] + ((ni + 2) << 11) + c0);
      b1[ni][1] = *(const bh8*)(bB[1] + ((ni + 2) << 11) + c1);
    }
    __builtin_amdgcn_s_barrier();
    __builtin_amdgcn_s_setprio(1);
    MM8(0, 2, b1)
    __builtin_amdgcn_s_setprio(0);
    __builtin_amdgcn_s_barrier();

    // ---- ph7: Q11(v); stage B(v+2,h0) ----
#pragma unroll
    for (int mi = 0; mi < 4; ++mi) {
      af[mi][0] = *(const bh8*)(bA[1] + ((mi + 4) << 11) + c0);
      af[mi][1] = *(const bh8*)(bA[1] + ((mi + 4) << 11) + c1);
    }
    if (more) STAGE(baseB, 0, 2 * j + 3, 6);
    __builtin_amdgcn_s_barrier();
    __builtin_amdgcn_s_setprio(1);
    MM8(4, 2, b1)
    __builtin_amdgcn_s_setprio(0);
    __builtin_amdgcn_s_barrier();

    // ---- ph8: Q10(v); stage B(v+2,h1)+A(v+2,h0); GATE (buf0 tile u+2) ----
    if (more) { STAGE(baseB, 1, 2 * j + 3, 7); STAGE(baseA, 0, 2 * j + 3, 4); }
    __builtin_amdgcn_s_barrier();
    __builtin_amdgcn_s_setprio(1);
    MM8(4, 0, b0)
    __builtin_amdgcn_s_setprio(0);
    if (more) {
      asm volatile("s_waitcnt vmcnt(6)" ::: "memory");
      __builtin_amdgcn_s_barrier();
    }
  }
}

// Gate GEMM: gates[g][m][n] = act(sum_d xn[m][d] * Wb[g][n][d])
__global__ __launch_bounds__(512, 2) void gemm_gates(const __hip_bfloat16* __restrict__ A,
                                                     const __hip_bfloat16* __restrict__ Wb,
                                                     __hip_bfloat16* __restrict__ G) {
  __shared__ ushort lds[8 * 8192];  // 128 KiB
  int gate = blockIdx.z;
  // XCD swizzle (nwg=352, 44/XCD) + 2-row-band bx-major order inside each
  // chunk: holds 2 A-panels (2 MB) in L2 while streaming each B-panel once.
  int lin = blockIdx.x + 11 * blockIdx.y;
  int wg = (lin & 7) * 44 + (lin >> 3);
  int band = wg / 22, r = wg % 22;
  int bx = r >> 1, by = band * 2 + (r & 1);
  int tile_n = bx * 256;
  int tile_m = by * 256;

  const ushort* Bm = (const ushort*)Wb + (size_t)gate * NP * D_;
  __hip_bfloat16* Gg = G + (size_t)gate * M_ * NP;

  fx4 acc[8][4];
#pragma unroll
  for (int i = 0; i < 8; ++i)
#pragma unroll
    for (int j = 0; j < 4; ++j) acc[i][j] = (fx4){0.f, 0.f, 0.f, 0.f};

  gemm256_core<D_, D_ / 64>((const ushort*)A, Bm, tile_m, tile_n, lds, acc);

  int lane = threadIdx.x & 63;
  int w = threadIdx.x >> 6;
  int wr = w >> 2, wc = w & 3;
  int g = lane >> 4;
#pragma unroll
  for (int mf = 0; mf < 8; ++mf) {
    int mbase = tile_m + wr * 128 + mf * 16 + (g << 2);
#pragma unroll
    for (int nf = 0; nf < 4; ++nf) {
      int n = tile_n + wc * 64 + nf * 16 + (lane & 15);
      bool valid = (n < P_);
#pragma unroll
      for (int r2 = 0; r2 < 4; ++r2) {
        float z = acc[mf][nf][r2];
        float val = (gate == 3) ? fast_tanh(z) : gate_act(z);
        if (!valid) val = 0.0f;
        Gg[(size_t)(mbase + r2) * NP + n] = __float2bfloat16(val);
      }
    }
  }
}

// Output GEMM: out[m][n] = x[m][n] + sum_p outbuf[m][p] * Woutb[n][p]
__global__ __launch_bounds__(512, 2) void gemm_out(const __hip_bfloat16* __restrict__ A,
                                                   const __hip_bfloat16* __restrict__ Bw,
                                                   const float* __restrict__ X,
                                                   float* __restrict__ Out) {
  __shared__ ushort lds[8 * 8192];
  // XCD swizzle (nwg=256, 32/XCD) + 2-row-band bx-major order
  int lin = blockIdx.x + 8 * blockIdx.y;
  int wg = (lin & 7) * 32 + (lin >> 3);
  int band = wg >> 4, r = wg & 15;
  int bx = r >> 1, by = band * 2 + (r & 1);
  int tile_n = bx * 256;
  int tile_m = by * 256;

  fx4 acc[8][4];
#pragma unroll
  for (int i = 0; i < 8; ++i)
#pragma unroll
    for (int j = 0; j < 4; ++j) acc[i][j] = (fx4){0.f, 0.f, 0.f, 0.f};

  gemm256_core<NP, NP / 64>((const ushort*)A, (const ushort*)Bw, tile_m, tile_n, lds, acc);

  int lane = threadIdx.x & 63;
  int w = threadIdx.x >> 6;
  int wr = w >> 2, wc = w & 3;
  int g = lane >> 4;
#pragma unroll
  for (int mf = 0; mf < 8; ++mf) {
    int mbase = tile_m + wr * 128 + mf * 16 + (g << 2);
#pragma unroll
    for (int nf = 0; nf < 4; ++nf) {
      int n = tile_n + wc * 64 + nf * 16 + (lane & 15);
#pragma unroll
      for (int r2 = 0; r2 < 4; ++r2) {
        size_t o = (size_t)(mbase + r2) * D_ + n;
        Out[o] = X[o] + acc[mf][nf][r2];
      }
    }
  }
}

// ---------------- chunked parallel LSTM scan (h = f*h + u is linear in h) ----------------
__global__ __launch_bounds__(256) void scan_pass1(const __hip_bfloat16* __restrict__ G,
                                                  float* __restrict__ Aa, float* __restrict__ Bb) {
  int idx = blockIdx.x * 256 + threadIdx.x;  // (b,p) flat
  int c = blockIdx.y;
  int b = idx / NP, p = idx - b * NP;
  size_t base = ((size_t)(b * S_ + c * SCHUNK)) * NP + p;
  const unsigned short* gi = (const unsigned short*)G + base;
  const size_t gs = (size_t)M_ * NP;
  const unsigned short* gf = gi + gs;
  const unsigned short* gc = gi + 3 * gs;
  float a = 1.f, acc = 0.f;
#pragma unroll 8
  for (int s = 0; s < SCHUNK; ++s) {
    size_t off = (size_t)s * NP;
    float fv = bf2f(gf[off]);
    float u = bf2f(gi[off]) * bf2f(gc[off]);
    acc = fv * acc + u;
    a *= fv;
  }
  int o = c * (B_ * NP) + idx;
  Aa[o] = a;
  Bb[o] = acc;
}

__global__ __launch_bounds__(256) void scan_mid(const float* __restrict__ Aa,
                                                const float* __restrict__ Bb,
                                                const float* __restrict__ h0,
                                                float* __restrict__ Hs,
                                                float* __restrict__ hfin) {
  int idx = blockIdx.x * 256 + threadIdx.x;
  int b = idx / NP, p = idx - b * NP;
  float h = (p < P_) ? h0[b * P_ + p] : 0.f;
#pragma unroll
  for (int c = 0; c < NCHUNK; ++c) {
    int o = c * (B_ * NP) + idx;
    Hs[o] = h;
    h = Aa[o] * h + Bb[o];
  }
  if (p < P_) hfin[b * P_ + p] = h;
}

__global__ __launch_bounds__(256) void scan_pass2(const __hip_bfloat16* __restrict__ G,
                                                  const float* __restrict__ Hs,
                                                  __hip_bfloat16* __restrict__ outb) {
  int idx = blockIdx.x * 256 + threadIdx.x;
  int c = blockIdx.y;
  int b = idx / NP, p = idx - b * NP;
  size_t base = ((size_t)(b * S_ + c * SCHUNK)) * NP + p;
  const unsigned short* gi = (const unsigned short*)G + base;
  const size_t gs = (size_t)M_ * NP;
  const unsigned short* gf = gi + gs;
  const unsigned short* go = gi + 2 * gs;
  const unsigned short* gc = gi + 3 * gs;
  unsigned short* ob = (unsigned short*)outb + base;
  float h = Hs[c * (B_ * NP) + idx];
#pragma unroll 4
  for (int s = 0; s < SCHUNK; ++s) {
    size_t off = (size_t)s * NP;
    float u = bf2f(gi[off]) * bf2f(gc[off]);
    h = bf2f(gf[off]) * h + u;
    ob[off] = f2bf(bf2f(go[off]) * fast_tanh(h));
  }
}

// ---------------- launch ----------------
extern "C" void kernel_launch(void* const* d_in, const int* in_sizes, int n_in,
                              void* d_out, int out_size, void* d_ws, size_t ws_size,
                              hipStream_t stream) {
  const float* x    = (const float*)d_in[0];
  const float* h0   = (const float*)d_in[1];
  const float* Wi   = (const float*)d_in[2];
  const float* Wf   = (const float*)d_in[3];
  const float* Wo   = (const float*)d_in[4];
  const float* Wc   = (const float*)d_in[5];
  const float* Wout = (const float*)d_in[6];
  const float* lnw  = (const float*)d_in[7];
  float* out  = (float*)d_out;
  float* hfin = out + (size_t)M_ * D_;

  const size_t wb_off    = (size_t)M_ * D_;                    // 16,777,216
  const size_t gates_off = wb_off + (size_t)4 * NP * D_;       // 39,845,888
  const size_t need = (gates_off + (size_t)4 * M_ * NP) * 2;   // bytes
  if (ws_size < need) {
    fprintf(stderr, "kernel_launch: ws too small (%zu < %zu)\n", ws_size, need);
    return;
  }
  __hip_bfloat16* ws     = (__hip_bfloat16*)d_ws;
  __hip_bfloat16* xn     = ws;
  __hip_bfloat16* Wb     = ws + wb_off;
  __hip_bfloat16* Gg     = ws + gates_off;
  __hip_bfloat16* outbuf = ws;                                  // aliases xn/Wb (dead)
  __hip_bfloat16* Woutb  = ws + (size_t)M_ * NP;
  float* scr = (float*)(ws + (size_t)M_ * NP + (size_t)D_ * NP);
  float* Aa = scr;
  float* Bb = Aa + NCHUNK * B_ * NP;
  float* Hs = Bb + NCHUNK * B_ * NP;

  convert_gate_w<<<dim3(NP * 512 / 256, 1, 4), 256, 0, stream>>>(Wi, Wf, Wo, Wc, Wb);
  rmsnorm_kernel<<<M_, 256, 0, stream>>>(x, lnw, xn);
  gemm_gates<<<dim3(NP / 256, M_ / 256, 4), 512, 0, stream>>>(xn, Wb, Gg);
  convert_wout<<<(int)(((size_t)D_ * NP + 255) / 256), 256, 0, stream>>>(Wout, Woutb);
  scan_pass1<<<dim3(B_ * NP / 256, NCHUNK), 256, 0, stream>>>(Gg, Aa, Bb);
  scan_mid<<<B_ * NP / 256, 256, 0, stream>>>(Aa, Bb, h0, Hs, hfin);
  scan_pass2<<<dim3(B_ * NP / 256, NCHUNK), 256, 0, stream>>>(Gg, Hs, outbuf);
  gemm_out<<<dim3(D_ / 256, M_ / 256), 512, 0, stream>>>(outbuf, Woutb, x, out);
}

// Round 5
// 693.777 us; speedup vs baseline: 1.8302x; 1.8302x over previous
//
#include <hip/hip_runtime.h>
#include <hip/hip_bf16.h>
#include <stdint.h>
#include <stdio.h>

// Problem sizes (fixed by setup_inputs)
#define B_ 4
#define S_ 2048
#define D_ 2048
#define P_ 2729
#define NP 2816            // P padded to multiple of 128
#define M_ (B_ * S_)       // 8192

#define SCHUNK 128
#define NCHUNK (S_ / SCHUNK)   // 16

// GEMM tile: 128x128, BK=64, 4 waves (2x2), XOR-swizzled LDS, 2-phase dbuf
#define BM 128
#define BN 128
#define BK 64

typedef __attribute__((ext_vector_type(8))) short bh8;   // 8 x bf16 (4 VGPRs)
typedef __attribute__((ext_vector_type(4))) float fx4;   // MFMA accumulator

static __device__ __forceinline__ float bf2f(unsigned short u) {
  union { unsigned int i; float f; } c;
  c.i = ((unsigned int)u) << 16;
  return c.f;
}
static __device__ __forceinline__ unsigned short f2bf(float f) {
  union { __hip_bfloat16 h; unsigned short u; } c;
  c.h = __float2bfloat16(f);
  return c.u;
}
static __device__ __forceinline__ float fast_tanh(float x) {
  return 1.0f - 2.0f / (__expf(2.0f * x) + 1.0f);
}
static __device__ __forceinline__ float gate_act(float z) {
  float sc = 15.0f * fast_tanh(z * (1.0f / 15.0f));
  return 1.0f / (1.0f + __expf(-sc));
}

static __device__ __forceinline__ void gload_lds16(const ushort* g, ushort* l) {
  __builtin_amdgcn_global_load_lds(
      (const __attribute__((address_space(1))) unsigned int*)g,
      (__attribute__((address_space(3))) unsigned int*)l, 16, 0, 0);
}

// ---------------- RMSNorm + bf16 cast ----------------
__global__ __launch_bounds__(256) void rmsnorm_kernel(const float* __restrict__ x,
                                                      const float* __restrict__ w,
                                                      __hip_bfloat16* __restrict__ xn) {
  int row = blockIdx.x;
  const float4* xr = (const float4*)(x + (size_t)row * D_);
  int t = threadIdx.x;
  float4 v0 = xr[t];
  float4 v1 = xr[t + 256];
  float ss = v0.x * v0.x + v0.y * v0.y + v0.z * v0.z + v0.w * v0.w +
             v1.x * v1.x + v1.y * v1.y + v1.z * v1.z + v1.w * v1.w;
#pragma unroll
  for (int off = 32; off > 0; off >>= 1) ss += __shfl_down(ss, off);
  __shared__ float red[4];
  if ((t & 63) == 0) red[t >> 6] = ss;
  __syncthreads();
  float scale = rsqrtf((red[0] + red[1] + red[2] + red[3]) * (1.0f / (float)D_) + 1e-6f);
  const float4* wp = (const float4*)w;
  float4 w0 = wp[t], w1 = wp[t + 256];
  ushort4 o0, o1;
  o0.x = f2bf(v0.x * scale * w0.x);
  o0.y = f2bf(v0.y * scale * w0.y);
  o0.z = f2bf(v0.z * scale * w0.z);
  o0.w = f2bf(v0.w * scale * w0.w);
  o1.x = f2bf(v1.x * scale * w1.x);
  o1.y = f2bf(v1.y * scale * w1.y);
  o1.z = f2bf(v1.z * scale * w1.z);
  o1.w = f2bf(v1.w * scale * w1.w);
  ushort4* xo = (ushort4*)(xn + (size_t)row * D_);
  xo[t] = o0;
  xo[t + 256] = o1;
}

// ---------------- weight conversion ----------------
__global__ __launch_bounds__(256) void convert_gate_w(const float* __restrict__ Wi,
                                                      const float* __restrict__ Wf,
                                                      const float* __restrict__ Wo,
                                                      const float* __restrict__ Wc,
                                                      __hip_bfloat16* __restrict__ Wb) {
  int g = blockIdx.z;
  const float* W = (g == 0) ? Wi : (g == 1) ? Wf : (g == 2) ? Wo : Wc;
  size_t u = (size_t)blockIdx.x * 256 + threadIdx.x;  // float4 index, NP*512 per gate
  int j = (int)(u >> 9);
  int q = (int)(u & 511);
  ushort4 o;
  if (j < P_) {
    float4 v = ((const float4*)(W + (size_t)j * D_))[q];
    o.x = f2bf(v.x); o.y = f2bf(v.y); o.z = f2bf(v.z); o.w = f2bf(v.w);
  } else {
    o.x = 0; o.y = 0; o.z = 0; o.w = 0;
  }
  ushort4* dst = (ushort4*)(Wb + (size_t)g * NP * D_ + (size_t)j * D_ + (size_t)q * 4);
  *dst = o;
}

__global__ __launch_bounds__(256) void convert_wout(const float* __restrict__ Wout,
                                                    __hip_bfloat16* __restrict__ Woutb) {
  size_t u = (size_t)blockIdx.x * 256 + threadIdx.x;
  if (u >= (size_t)D_ * NP) return;
  int d = (int)(u / NP);
  int p = (int)(u - (size_t)d * NP);
  float v = (p < P_) ? Wout[(size_t)d * P_ + p] : 0.0f;
  Woutb[u] = __float2bfloat16(v);
}

// ---------------- GEMM core (C = A * B^T), bf16, 128x128, BK=64, 2-phase dbuf ----------------
// A: [M][LD] row-major, B: [N][LD] row-major (K contiguous both).
// LDS: 2 buffers x (A-tile + B-tile) of [128 rows][64 cols] bf16 (16 KB each) = 64 KB.
// XOR swizzle (byte ^= (row&7)<<4) on reads; gload_lds dest LINEAR with
// pre-swizzled GLOBAL source column (rule #21: same involution both sides).
// T3 minimum-2-phase recipe: issue STAGE(next tile -> other buffer) BEFORE the
// ds_read+MFMA of the current buffer, then ONE __syncthreads per K-step (its
// implicit vmcnt(0)+lgkmcnt(0) drain comes a full compute phase after the
// stage was issued, so the drain stall amortizes; dbuf makes 1 barrier safe:
// the buffer being overwritten next phase was last READ before this barrier).
template <int LD, int KTOT>
static __device__ __forceinline__ void gemm_core(const ushort* __restrict__ A,
                                                 const ushort* __restrict__ Bm,
                                                 int tile_m, int tile_n,
                                                 ushort* lds,   // 4*8192 ushorts
                                                 fx4 (&acc)[4][4]) {
  const int t = threadIdx.x;
  const int lane = t & 63;
  const int w = t >> 6;
  const int wr = w >> 1, wc = w & 1;
  const int frow = lane & 15;
  const int g = lane >> 4;
  const int xr = (frow & 7) << 4;

  ushort* A0 = lds;
  ushort* B0 = lds + 8192;
  ushort* A1 = lds + 16384;
  ushort* B1 = lds + 24576;

  // staging: thread t, round q: LDS elements (q*256+t)*8 (linear),
  // row r = (q*256+t)>>3, global col = ((t&7) ^ (r&7)) * 8 + k0
  const ushort* gA[4];
  const ushort* gB[4];
  int ldsoff[4];
#pragma unroll
  for (int q = 0; q < 4; ++q) {
    int u = q * 256 + t;
    int r = u >> 3;
    int gc = ((t & 7) ^ (r & 7)) << 3;
    gA[q] = A + (size_t)(tile_m + r) * LD + gc;
    gB[q] = Bm + (size_t)(tile_n + r) * LD + gc;
    ldsoff[q] = u * 8;
  }

  auto STAGE = [&](int k0, ushort* dA, ushort* dB) {
#pragma unroll
    for (int q = 0; q < 4; ++q) gload_lds16(gA[q] + k0, dA + ldsoff[q]);
#pragma unroll
    for (int q = 0; q < 4; ++q) gload_lds16(gB[q] + k0, dB + ldsoff[q]);
  };

  const int rowA = (wr * 64 + frow) << 7;
  const int rowB = (wc * 64 + frow) << 7;
  const int c0 = (g << 4) ^ xr;        // kk=0 16B slot (swizzled)
  const int c1 = (64 + (g << 4)) ^ xr; // kk=1 16B slot (swizzled)

  auto COMPUTE = [&](const ushort* bufA, const ushort* bufB) {
    const char* baseA = (const char*)bufA + rowA;
    const char* baseB = (const char*)bufB + rowB;
    bh8 af[4][2], bf[4][2];
#pragma unroll
    for (int mf = 0; mf < 4; ++mf) {
      af[mf][0] = *(const bh8*)(baseA + (mf << 11) + c0);
      af[mf][1] = *(const bh8*)(baseA + (mf << 11) + c1);
    }
#pragma unroll
    for (int nf = 0; nf < 4; ++nf) {
      bf[nf][0] = *(const bh8*)(baseB + (nf << 11) + c0);
      bf[nf][1] = *(const bh8*)(baseB + (nf << 11) + c1);
    }
#pragma unroll
    for (int mf = 0; mf < 4; ++mf)
#pragma unroll
      for (int nf = 0; nf < 4; ++nf) {
        acc[mf][nf] = __builtin_amdgcn_mfma_f32_16x16x32_bf16(af[mf][0], bf[nf][0], acc[mf][nf], 0, 0, 0);
        acc[mf][nf] = __builtin_amdgcn_mfma_f32_16x16x32_bf16(af[mf][1], bf[nf][1], acc[mf][nf], 0, 0, 0);
      }
  };

  // KTOT is a multiple of 128 (2048, 2816)
  STAGE(0, A0, B0);
  __syncthreads();
  for (int k0 = 0; k0 < KTOT; k0 += 128) {
    const bool haveB = (k0 + 64 < KTOT);   // always true given KTOT%128==0
    const bool haveC = (k0 + 128 < KTOT);
    if (haveB) STAGE(k0 + 64, A1, B1);     // prefetch odd tile into buf1
    COMPUTE(A0, B0);
    __syncthreads();                        // buf1 staged complete; buf0 reads done
    if (haveC) STAGE(k0 + 128, A0, B0);    // prefetch next even tile into buf0
    if (haveB) COMPUTE(A1, B1);
    if (haveC) __syncthreads();            // buf0 staged complete; buf1 reads done
  }
}

// Gate GEMM: gates[g][m][n] = act(sum_d xn[m][d] * Wb[g][n][d])
__global__ __launch_bounds__(256) void gemm_gates(const __hip_bfloat16* __restrict__ A,
                                                  const __hip_bfloat16* __restrict__ Wb,
                                                  __hip_bfloat16* __restrict__ G) {
  int gate = blockIdx.z;
  // XCD band order: lin -> (xcd = lin&7) owns m-rows [8*xcd, 8*xcd+8);
  // within XCD iterate bx outer, my inner -> A-slice 8x128 rows x 2048 x 2B
  // = 4 MB resident in that XCD's L2; each B col-tile streamed once per XCD
  // (B panel 11.5 MB is L3-resident across XCDs).
  int lin = blockIdx.x + 22 * blockIdx.y;   // 0..1407
  int xcd = lin & 7;
  int idx = lin >> 3;                       // 0..175
  int bx = idx >> 3;                        // 0..21
  int my = idx & 7;
  int by = xcd * 8 + my;                    // 0..63
  int tile_n = bx * BN;
  int tile_m = by * BM;

  const ushort* Bm = (const ushort*)Wb + (size_t)gate * NP * D_;
  __hip_bfloat16* Gg = G + (size_t)gate * M_ * NP;

  __shared__ ushort lds[4 * 8192];  // 64 KiB

  fx4 acc[4][4];
#pragma unroll
  for (int i = 0; i < 4; ++i)
#pragma unroll
    for (int j = 0; j < 4; ++j) acc[i][j] = (fx4){0.f, 0.f, 0.f, 0.f};

  gemm_core<D_, D_>((const ushort*)A, Bm, tile_m, tile_n, lds, acc);

  int lane = threadIdx.x & 63;
  int w = threadIdx.x >> 6;
  int wr = w >> 1, wc = w & 1;
#pragma unroll
  for (int mf = 0; mf < 4; ++mf) {
    int mbase = tile_m + wr * 64 + mf * 16 + ((lane >> 4) << 2);
#pragma unroll
    for (int nf = 0; nf < 4; ++nf) {
      int n = tile_n + wc * 64 + nf * 16 + (lane & 15);
      bool valid = (n < P_);
#pragma unroll
      for (int r = 0; r < 4; ++r) {
        float z = acc[mf][nf][r];
        float val = (gate == 3) ? fast_tanh(z) : gate_act(z);
        if (!valid) val = 0.0f;
        Gg[(size_t)(mbase + r) * NP + n] = __float2bfloat16(val);
      }
    }
  }
}

// Output GEMM: out[m][n] = x[m][n] + sum_p outbuf[m][p] * Woutb[n][p]
__global__ __launch_bounds__(256) void gemm_out(const __hip_bfloat16* __restrict__ A,
                                               const __hip_bfloat16* __restrict__ Bw,
                                               const float* __restrict__ X,
                                               float* __restrict__ Out) {
  // XCD band order: grid 16 x 64; xcd owns 8 m-rows, bx outer / my inner
  int lin = blockIdx.x + 16 * blockIdx.y;   // 0..1023
  int xcd = lin & 7;
  int idx = lin >> 3;                       // 0..127
  int bx = idx >> 3;                        // 0..15
  int my = idx & 7;
  int by = xcd * 8 + my;                    // 0..63
  int tile_n = bx * BN;
  int tile_m = by * BM;

  __shared__ ushort lds[4 * 8192];

  fx4 acc[4][4];
#pragma unroll
  for (int i = 0; i < 4; ++i)
#pragma unroll
    for (int j = 0; j < 4; ++j) acc[i][j] = (fx4){0.f, 0.f, 0.f, 0.f};

  gemm_core<NP, NP>((const ushort*)A, (const ushort*)Bw, tile_m, tile_n, lds, acc);

  int lane = threadIdx.x & 63;
  int w = threadIdx.x >> 6;
  int wr = w >> 1, wc = w & 1;
#pragma unroll
  for (int mf = 0; mf < 4; ++mf) {
    int mbase = tile_m + wr * 64 + mf * 16 + ((lane >> 4) << 2);
#pragma unroll
    for (int nf = 0; nf < 4; ++nf) {
      int n = tile_n + wc * 64 + nf * 16 + (lane & 15);
#pragma unroll
      for (int r = 0; r < 4; ++r) {
        size_t o = (size_t)(mbase + r) * D_ + n;
        Out[o] = X[o] + acc[mf][nf][r];
      }
    }
  }
}

// ---------------- chunked parallel LSTM scan (h = f*h + u is linear in h) ----------------
__global__ __launch_bounds__(256) void scan_pass1(const __hip_bfloat16* __restrict__ G,
                                                  float* __restrict__ Aa, float* __restrict__ Bb) {
  int idx = blockIdx.x * 256 + threadIdx.x;  // (b,p) flat
  int c = blockIdx.y;
  int b = idx / NP, p = idx - b * NP;
  size_t base = ((size_t)(b * S_ + c * SCHUNK)) * NP + p;
  const unsigned short* gi = (const unsigned short*)G + base;
  const size_t gs = (size_t)M_ * NP;
  const unsigned short* gf = gi + gs;
  const unsigned short* gc = gi + 3 * gs;
  float a = 1.f, acc = 0.f;
#pragma unroll 8
  for (int s = 0; s < SCHUNK; ++s) {
    size_t off = (size_t)s * NP;
    float fv = bf2f(gf[off]);
    float u = bf2f(gi[off]) * bf2f(gc[off]);
    acc = fv * acc + u;
    a *= fv;
  }
  int o = c * (B_ * NP) + idx;
  Aa[o] = a;
  Bb[o] = acc;
}

__global__ __launch_bounds__(256) void scan_mid(const float* __restrict__ Aa,
                                                const float* __restrict__ Bb,
                                                const float* __restrict__ h0,
                                                float* __restrict__ Hs,
                                                float* __restrict__ hfin) {
  int idx = blockIdx.x * 256 + threadIdx.x;
  int b = idx / NP, p = idx - b * NP;
  float h = (p < P_) ? h0[b * P_ + p] : 0.f;
#pragma unroll
  for (int c = 0; c < NCHUNK; ++c) {
    int o = c * (B_ * NP) + idx;
    Hs[o] = h;
    h = Aa[o] * h + Bb[o];
  }
  if (p < P_) hfin[b * P_ + p] = h;
}

__global__ __launch_bounds__(256) void scan_pass2(const __hip_bfloat16* __restrict__ G,
                                                  const float* __restrict__ Hs,
                                                  __hip_bfloat16* __restrict__ outb) {
  int idx = blockIdx.x * 256 + threadIdx.x;
  int c = blockIdx.y;
  int b = idx / NP, p = idx - b * NP;
  size_t base = ((size_t)(b * S_ + c * SCHUNK)) * NP + p;
  const unsigned short* gi = (const unsigned short*)G + base;
  const size_t gs = (size_t)M_ * NP;
  const unsigned short* gf = gi + gs;
  const unsigned short* go = gi + 2 * gs;
  const unsigned short* gc = gi + 3 * gs;
  unsigned short* ob = (unsigned short*)outb + base;
  float h = Hs[c * (B_ * NP) + idx];
#pragma unroll 4
  for (int s = 0; s < SCHUNK; ++s) {
    size_t off = (size_t)s * NP;
    float u = bf2f(gi[off]) * bf2f(gc[off]);
    h = bf2f(gf[off]) * h + u;
    ob[off] = f2bf(bf2f(go[off]) * fast_tanh(h));
  }
}

// ---------------- launch ----------------
extern "C" void kernel_launch(void* const* d_in, const int* in_sizes, int n_in,
                              void* d_out, int out_size, void* d_ws, size_t ws_size,
                              hipStream_t stream) {
  const float* x    = (const float*)d_in[0];
  const float* h0   = (const float*)d_in[1];
  const float* Wi   = (const float*)d_in[2];
  const float* Wf   = (const float*)d_in[3];
  const float* Wo   = (const float*)d_in[4];
  const float* Wc   = (const float*)d_in[5];
  const float* Wout = (const float*)d_in[6];
  const float* lnw  = (const float*)d_in[7];
  float* out  = (float*)d_out;
  float* hfin = out + (size_t)M_ * D_;

  const size_t wb_off    = (size_t)M_ * D_;                    // 16,777,216
  const size_t gates_off = wb_off + (size_t)4 * NP * D_;       // 39,845,888
  const size_t need = (gates_off + (size_t)4 * M_ * NP) * 2;   // bytes
  if (ws_size < need) {
    fprintf(stderr, "kernel_launch: ws too small (%zu < %zu)\n", ws_size, need);
    return;
  }
  __hip_bfloat16* ws     = (__hip_bfloat16*)d_ws;
  __hip_bfloat16* xn     = ws;
  __hip_bfloat16* Wb     = ws + wb_off;
  __hip_bfloat16* Gg     = ws + gates_off;
  __hip_bfloat16* outbuf = ws;                                  // aliases xn/Wb (dead)
  __hip_bfloat16* Woutb  = ws + (size_t)M_ * NP;
  float* scr = (float*)(ws + (size_t)M_ * NP + (size_t)D_ * NP);
  float* Aa = scr;
  float* Bb = Aa + NCHUNK * B_ * NP;
  float* Hs = Bb + NCHUNK * B_ * NP;

  convert_gate_w<<<dim3(NP * 512 / 256, 1, 4), 256, 0, stream>>>(Wi, Wf, Wo, Wc, Wb);
  rmsnorm_kernel<<<M_, 256, 0, stream>>>(x, lnw, xn);
  gemm_gates<<<dim3(NP / BN, M_ / BM, 4), 256, 0, stream>>>(xn, Wb, Gg);
  convert_wout<<<(int)(((size_t)D_ * NP + 255) / 256), 256, 0, stream>>>(Wout, Woutb);
  scan_pass1<<<dim3(B_ * NP / 256, NCHUNK), 256, 0, stream>>>(Gg, Aa, Bb);
  scan_mid<<<B_ * NP / 256, 256, 0, stream>>>(Aa, Bb, h0, Hs, hfin);
  scan_pass2<<<dim3(B_ * NP / 256, NCHUNK), 256, 0, stream>>>(Gg, Hs, outbuf);
  gemm_out<<<dim3(D_ / BN, M_ / BM), 256, 0, stream>>>(outbuf, Woutb, x, out);
}

// Round 6
// 627.860 us; speedup vs baseline: 2.0224x; 1.1050x over previous
//
#include <hip/hip_runtime.h>
#include <hip/hip_bf16.h>
#include <stdint.h>
#include <stdio.h>

// Problem sizes (fixed by setup_inputs)
#define B_ 4
#define S_ 2048
#define D_ 2048
#define P_ 2729
#define NP 2816            // P padded to multiple of 256
#define M_ (B_ * S_)       // 8192

#define SCHUNK 128
#define NCHUNK (S_ / SCHUNK)   // 16

typedef __attribute__((ext_vector_type(8))) short bh8;   // 8 x bf16 (4 VGPRs)
typedef __attribute__((ext_vector_type(4))) float fx4;   // MFMA accumulator

static __device__ __forceinline__ float bf2f(unsigned short u) {
  union { unsigned int i; float f; } c;
  c.i = ((unsigned int)u) << 16;
  return c.f;
}
static __device__ __forceinline__ unsigned short f2bf(float f) {
  union { __hip_bfloat16 h; unsigned short u; } c;
  c.h = __float2bfloat16(f);
  return c.u;
}
static __device__ __forceinline__ float fast_tanh(float x) {
  return 1.0f - 2.0f / (__expf(2.0f * x) + 1.0f);
}
static __device__ __forceinline__ float gate_act(float z) {
  float sc = 15.0f * fast_tanh(z * (1.0f / 15.0f));
  return 1.0f / (1.0f + __expf(-sc));
}

static __device__ __forceinline__ void gload_lds16(const ushort* g, ushort* l) {
  __builtin_amdgcn_global_load_lds(
      (const __attribute__((address_space(1))) unsigned int*)g,
      (__attribute__((address_space(3))) unsigned int*)l, 16, 0, 0);
}

// ---------------- RMSNorm + bf16 cast ----------------
__global__ __launch_bounds__(256) void rmsnorm_kernel(const float* __restrict__ x,
                                                      const float* __restrict__ w,
                                                      __hip_bfloat16* __restrict__ xn) {
  int row = blockIdx.x;
  const float4* xr = (const float4*)(x + (size_t)row * D_);
  int t = threadIdx.x;
  float4 v0 = xr[t];
  float4 v1 = xr[t + 256];
  float ss = v0.x * v0.x + v0.y * v0.y + v0.z * v0.z + v0.w * v0.w +
             v1.x * v1.x + v1.y * v1.y + v1.z * v1.z + v1.w * v1.w;
#pragma unroll
  for (int off = 32; off > 0; off >>= 1) ss += __shfl_down(ss, off);
  __shared__ float red[4];
  if ((t & 63) == 0) red[t >> 6] = ss;
  __syncthreads();
  float scale = rsqrtf((red[0] + red[1] + red[2] + red[3]) * (1.0f / (float)D_) + 1e-6f);
  const float4* wp = (const float4*)w;
  float4 w0 = wp[t], w1 = wp[t + 256];
  ushort4 o0, o1;
  o0.x = f2bf(v0.x * scale * w0.x);
  o0.y = f2bf(v0.y * scale * w0.y);
  o0.z = f2bf(v0.z * scale * w0.z);
  o0.w = f2bf(v0.w * scale * w0.w);
  o1.x = f2bf(v1.x * scale * w1.x);
  o1.y = f2bf(v1.y * scale * w1.y);
  o1.z = f2bf(v1.z * scale * w1.z);
  o1.w = f2bf(v1.w * scale * w1.w);
  ushort4* xo = (ushort4*)(xn + (size_t)row * D_);
  xo[t] = o0;
  xo[t + 256] = o1;
}

// ---------------- weight conversion ----------------
__global__ __launch_bounds__(256) void convert_gate_w(const float* __restrict__ Wi,
                                                      const float* __restrict__ Wf,
                                                      const float* __restrict__ Wo,
                                                      const float* __restrict__ Wc,
                                                      __hip_bfloat16* __restrict__ Wb) {
  int g = blockIdx.z;
  const float* W = (g == 0) ? Wi : (g == 1) ? Wf : (g == 2) ? Wo : Wc;
  size_t u = (size_t)blockIdx.x * 256 + threadIdx.x;  // float4 index, NP*512 per gate
  int j = (int)(u >> 9);
  int q = (int)(u & 511);
  ushort4 o;
  if (j < P_) {
    float4 v = ((const float4*)(W + (size_t)j * D_))[q];
    o.x = f2bf(v.x); o.y = f2bf(v.y); o.z = f2bf(v.z); o.w = f2bf(v.w);
  } else {
    o.x = 0; o.y = 0; o.z = 0; o.w = 0;
  }
  ushort4* dst = (ushort4*)(Wb + (size_t)g * NP * D_ + (size_t)j * D_ + (size_t)q * 4);
  *dst = o;
}

__global__ __launch_bounds__(256) void convert_wout(const float* __restrict__ Wout,
                                                    __hip_bfloat16* __restrict__ Woutb) {
  size_t u = (size_t)blockIdx.x * 256 + threadIdx.x;
  if (u >= (size_t)D_ * NP) return;
  int d = (int)(u / NP);
  int p = (int)(u - (size_t)d * NP);
  float v = (p < P_) ? Wout[(size_t)d * P_ + p] : 0.0f;
  Woutb[u] = __float2bfloat16(v);
}

// ---------------- GEMM core (C = A * B^T), bf16, 256x256 tile, BK=64, 2-phase dbuf ----------------
// A: [M][LD] row-major, B: [N][LD] row-major (K contiguous both).
// 512 threads = 8 waves (2M x 4N); per-wave output 128x64 (intensity
// Wm*Wn/(Wm+Wn) = 42.7 vs 32 for 64x64 -> ~33% less LDS-read traffic per FLOP,
// and staging writes per FLOP halve with the 2x tile area).
// LDS: 2 buffers x (A[256][64] + B[256][64]) bf16 = 128 KB static.
// XOR swizzle (byte ^= (row&7)<<4) on reads; gload_lds dest LINEAR with
// pre-swizzled GLOBAL source column (rule #21: same involution both sides).
// Schedule = round-5-proven: issue STAGE(next->other buf) BEFORE compute of
// current buf, ONE __syncthreads per K-step (implicit vmcnt/lgkm drain comes a
// full compute phase after the stage was issued -> drain amortized; dbuf makes
// 1 barrier safe: buffer overwritten next step was read before this barrier).
template <int LD, int KTOT>
static __device__ __forceinline__ void gemm_core(const ushort* __restrict__ A,
                                                 const ushort* __restrict__ Bm,
                                                 int tile_m, int tile_n,
                                                 ushort* lds,   // 65536 ushorts
                                                 fx4 (&acc)[8][4]) {
  const int t = threadIdx.x;       // 0..511
  const int lane = t & 63;
  const int w = t >> 6;            // 0..7
  const int wr = w >> 2, wc = w & 3;
  const int frow = lane & 15;
  const int g = lane >> 4;
  const int xr = (frow & 7) << 4;

  ushort* A0 = lds;
  ushort* B0 = lds + 16384;
  ushort* A1 = lds + 32768;
  ushort* B1 = lds + 49152;

  // staging: thread t, round q: LDS elements (q*512+t)*8 (linear),
  // row r = (q*512+t)>>3, source col = ((t&7) ^ (r&7)) * 8 + k0
  const ushort* gA[4];
  const ushort* gB[4];
  int ldsoff[4];
#pragma unroll
  for (int q = 0; q < 4; ++q) {
    int u = q * 512 + t;
    int r = u >> 3;
    int gc = ((t & 7) ^ (r & 7)) << 3;
    gA[q] = A + (size_t)(tile_m + r) * LD + gc;
    gB[q] = Bm + (size_t)(tile_n + r) * LD + gc;
    ldsoff[q] = u * 8;
  }

  auto STAGE = [&](int k0, ushort* dA, ushort* dB) {
#pragma unroll
    for (int q = 0; q < 4; ++q) gload_lds16(gA[q] + k0, dA + ldsoff[q]);
#pragma unroll
    for (int q = 0; q < 4; ++q) gload_lds16(gB[q] + k0, dB + ldsoff[q]);
  };

  const int rowA = (wr * 128 + frow) << 7;
  const int rowB = (wc * 64 + frow) << 7;
  const int c0 = (g << 4) ^ xr;        // kk=0 16B slot (swizzled)
  const int c1 = (64 + (g << 4)) ^ xr; // kk=1 16B slot (swizzled)

  auto COMPUTE = [&](const ushort* bufA, const ushort* bufB) {
    const char* baseA = (const char*)bufA + rowA;
    const char* baseB = (const char*)bufB + rowB;
    bh8 bfr[4][2];
#pragma unroll
    for (int nf = 0; nf < 4; ++nf) {
      bfr[nf][0] = *(const bh8*)(baseB + (nf << 11) + c0);
      bfr[nf][1] = *(const bh8*)(baseB + (nf << 11) + c1);
    }
#pragma unroll
    for (int mh = 0; mh < 2; ++mh) {
      bh8 af[4][2];
#pragma unroll
      for (int mi = 0; mi < 4; ++mi) {
        af[mi][0] = *(const bh8*)(baseA + ((mh * 4 + mi) << 11) + c0);
        af[mi][1] = *(const bh8*)(baseA + ((mh * 4 + mi) << 11) + c1);
      }
#pragma unroll
      for (int mi = 0; mi < 4; ++mi)
#pragma unroll
        for (int nf = 0; nf < 4; ++nf) {
          acc[mh * 4 + mi][nf] = __builtin_amdgcn_mfma_f32_16x16x32_bf16(
              af[mi][0], bfr[nf][0], acc[mh * 4 + mi][nf], 0, 0, 0);
          acc[mh * 4 + mi][nf] = __builtin_amdgcn_mfma_f32_16x16x32_bf16(
              af[mi][1], bfr[nf][1], acc[mh * 4 + mi][nf], 0, 0, 0);
        }
    }
  };

  // KTOT is a multiple of 128 (2048, 2816)
  STAGE(0, A0, B0);
  __syncthreads();
  for (int k0 = 0; k0 < KTOT; k0 += 128) {
    const bool haveC = (k0 + 128 < KTOT);
    STAGE(k0 + 64, A1, B1);                // prefetch odd tile into buf1
    COMPUTE(A0, B0);
    __syncthreads();                       // buf1 staged complete; buf0 reads done
    if (haveC) STAGE(k0 + 128, A0, B0);    // prefetch next even tile into buf0
    COMPUTE(A1, B1);
    if (haveC) __syncthreads();            // buf0 staged complete; buf1 reads done
  }
}

// Gate GEMM: gates[g][m][n] = act(sum_d xn[m][d] * Wb[g][n][d])
__global__ __launch_bounds__(512, 2) void gemm_gates(const __hip_bfloat16* __restrict__ A,
                                                     const __hip_bfloat16* __restrict__ Wb,
                                                     __hip_bfloat16* __restrict__ G) {
  __shared__ ushort lds[4 * 16384];  // 128 KiB
  int gate = blockIdx.z;
  // XCD band order: xcd = lin&7 owns 4 consecutive by-rows (A-slice
  // 4*256 rows x 2048 x 2B = 4 MB = one XCD L2); bx outer, by inner.
  int lin = blockIdx.x + 11 * blockIdx.y;   // 0..351
  int xcd = lin & 7;
  int idx = lin >> 3;                       // 0..43
  int bx = idx % 11;
  int by = xcd * 4 + idx / 11;              // 0..31
  int tile_n = bx * 256;
  int tile_m = by * 256;

  const ushort* Bm = (const ushort*)Wb + (size_t)gate * NP * D_;
  __hip_bfloat16* Gg = G + (size_t)gate * M_ * NP;

  fx4 acc[8][4];
#pragma unroll
  for (int i = 0; i < 8; ++i)
#pragma unroll
    for (int j = 0; j < 4; ++j) acc[i][j] = (fx4){0.f, 0.f, 0.f, 0.f};

  gemm_core<D_, D_>((const ushort*)A, Bm, tile_m, tile_n, lds, acc);

  int lane = threadIdx.x & 63;
  int w = threadIdx.x >> 6;
  int wr = w >> 2, wc = w & 3;
  int g = lane >> 4;
#pragma unroll
  for (int mf = 0; mf < 8; ++mf) {
    int mbase = tile_m + wr * 128 + mf * 16 + (g << 2);
#pragma unroll
    for (int nf = 0; nf < 4; ++nf) {
      int n = tile_n + wc * 64 + nf * 16 + (lane & 15);
      bool valid = (n < P_);
#pragma unroll
      for (int r = 0; r < 4; ++r) {
        float z = acc[mf][nf][r];
        float val = (gate == 3) ? fast_tanh(z) : gate_act(z);
        if (!valid) val = 0.0f;
        Gg[(size_t)(mbase + r) * NP + n] = __float2bfloat16(val);
      }
    }
  }
}

// Output GEMM: out[m][n] = x[m][n] + sum_p outbuf[m][p] * Woutb[n][p]
__global__ __launch_bounds__(512, 2) void gemm_out(const __hip_bfloat16* __restrict__ A,
                                                   const __hip_bfloat16* __restrict__ Bw,
                                                   const float* __restrict__ X,
                                                   float* __restrict__ Out) {
  __shared__ ushort lds[4 * 16384];
  // XCD band order: grid 8 x 32; xcd owns 4 by-rows, bx outer / by inner
  int lin = blockIdx.x + 8 * blockIdx.y;    // 0..255
  int xcd = lin & 7;
  int idx = lin >> 3;                       // 0..31
  int bx = idx & 7;
  int by = xcd * 4 + (idx >> 3);            // 0..31
  int tile_n = bx * 256;
  int tile_m = by * 256;

  fx4 acc[8][4];
#pragma unroll
  for (int i = 0; i < 8; ++i)
#pragma unroll
    for (int j = 0; j < 4; ++j) acc[i][j] = (fx4){0.f, 0.f, 0.f, 0.f};

  gemm_core<NP, NP>((const ushort*)A, (const ushort*)Bw, tile_m, tile_n, lds, acc);

  int lane = threadIdx.x & 63;
  int w = threadIdx.x >> 6;
  int wr = w >> 2, wc = w & 3;
  int g = lane >> 4;
#pragma unroll
  for (int mf = 0; mf < 8; ++mf) {
    int mbase = tile_m + wr * 128 + mf * 16 + (g << 2);
#pragma unroll
    for (int nf = 0; nf < 4; ++nf) {
      int n = tile_n + wc * 64 + nf * 16 + (lane & 15);
#pragma unroll
      for (int r = 0; r < 4; ++r) {
        size_t o = (size_t)(mbase + r) * D_ + n;
        Out[o] = X[o] + acc[mf][nf][r];
      }
    }
  }
}

// ---------------- chunked parallel LSTM scan (h = f*h + u is linear in h) ----------------
__global__ __launch_bounds__(256) void scan_pass1(const __hip_bfloat16* __restrict__ G,
                                                  float* __restrict__ Aa, float* __restrict__ Bb) {
  int idx = blockIdx.x * 256 + threadIdx.x;  // (b,p) flat
  int c = blockIdx.y;
  int b = idx / NP, p = idx - b * NP;
  size_t base = ((size_t)(b * S_ + c * SCHUNK)) * NP + p;
  const unsigned short* gi = (const unsigned short*)G + base;
  const size_t gs = (size_t)M_ * NP;
  const unsigned short* gf = gi + gs;
  const unsigned short* gc = gi + 3 * gs;
  float a = 1.f, acc = 0.f;
#pragma unroll 8
  for (int s = 0; s < SCHUNK; ++s) {
    size_t off = (size_t)s * NP;
    float fv = bf2f(gf[off]);
    float u = bf2f(gi[off]) * bf2f(gc[off]);
    acc = fv * acc + u;
    a *= fv;
  }
  int o = c * (B_ * NP) + idx;
  Aa[o] = a;
  Bb[o] = acc;
}

__global__ __launch_bounds__(256) void scan_mid(const float* __restrict__ Aa,
                                                const float* __restrict__ Bb,
                                                const float* __restrict__ h0,
                                                float* __restrict__ Hs,
                                                float* __restrict__ hfin) {
  int idx = blockIdx.x * 256 + threadIdx.x;
  int b = idx / NP, p = idx - b * NP;
  float h = (p < P_) ? h0[b * P_ + p] : 0.f;
#pragma unroll
  for (int c = 0; c < NCHUNK; ++c) {
    int o = c * (B_ * NP) + idx;
    Hs[o] = h;
    h = Aa[o] * h + Bb[o];
  }
  if (p < P_) hfin[b * P_ + p] = h;
}

__global__ __launch_bounds__(256) void scan_pass2(const __hip_bfloat16* __restrict__ G,
                                                  const float* __restrict__ Hs,
                                                  __hip_bfloat16* __restrict__ outb) {
  int idx = blockIdx.x * 256 + threadIdx.x;
  int c = blockIdx.y;
  int b = idx / NP, p = idx - b * NP;
  size_t base = ((size_t)(b * S_ + c * SCHUNK)) * NP + p;
  const unsigned short* gi = (const unsigned short*)G + base;
  const size_t gs = (size_t)M_ * NP;
  const unsigned short* gf = gi + gs;
  const unsigned short* go = gi + 2 * gs;
  const unsigned short* gc = gi + 3 * gs;
  unsigned short* ob = (unsigned short*)outb + base;
  float h = Hs[c * (B_ * NP) + idx];
#pragma unroll 4
  for (int s = 0; s < SCHUNK; ++s) {
    size_t off = (size_t)s * NP;
    float u = bf2f(gi[off]) * bf2f(gc[off]);
    h = bf2f(gf[off]) * h + u;
    ob[off] = f2bf(bf2f(go[off]) * fast_tanh(h));
  }
}

// ---------------- launch ----------------
extern "C" void kernel_launch(void* const* d_in, const int* in_sizes, int n_in,
                              void* d_out, int out_size, void* d_ws, size_t ws_size,
                              hipStream_t stream) {
  const float* x    = (const float*)d_in[0];
  const float* h0   = (const float*)d_in[1];
  const float* Wi   = (const float*)d_in[2];
  const float* Wf   = (const float*)d_in[3];
  const float* Wo   = (const float*)d_in[4];
  const float* Wc   = (const float*)d_in[5];
  const float* Wout = (const float*)d_in[6];
  const float* lnw  = (const float*)d_in[7];
  float* out  = (float*)d_out;
  float* hfin = out + (size_t)M_ * D_;

  const size_t wb_off    = (size_t)M_ * D_;                    // 16,777,216
  const size_t gates_off = wb_off + (size_t)4 * NP * D_;       // 39,845,888
  const size_t need = (gates_off + (size_t)4 * M_ * NP) * 2;   // bytes
  if (ws_size < need) {
    fprintf(stderr, "kernel_launch: ws too small (%zu < %zu)\n", ws_size, need);
    return;
  }
  __hip_bfloat16* ws     = (__hip_bfloat16*)d_ws;
  __hip_bfloat16* xn     = ws;
  __hip_bfloat16* Wb     = ws + wb_off;
  __hip_bfloat16* Gg     = ws + gates_off;
  __hip_bfloat16* outbuf = ws;                                  // aliases xn/Wb (dead)
  __hip_bfloat16* Woutb  = ws + (size_t)M_ * NP;
  float* scr = (float*)(ws + (size_t)M_ * NP + (size_t)D_ * NP);
  float* Aa = scr;
  float* Bb = Aa + NCHUNK * B_ * NP;
  float* Hs = Bb + NCHUNK * B_ * NP;

  convert_gate_w<<<dim3(NP * 512 / 256, 1, 4), 256, 0, stream>>>(Wi, Wf, Wo, Wc, Wb);
  rmsnorm_kernel<<<M_, 256, 0, stream>>>(x, lnw, xn);
  gemm_gates<<<dim3(NP / 256, M_ / 256, 4), 512, 0, stream>>>(xn, Wb, Gg);
  convert_wout<<<(int)(((size_t)D_ * NP + 255) / 256), 256, 0, stream>>>(Wout, Woutb);
  scan_pass1<<<dim3(B_ * NP / 256, NCHUNK), 256, 0, stream>>>(Gg, Aa, Bb);
  scan_mid<<<B_ * NP / 256, 256, 0, stream>>>(Aa, Bb, h0, Hs, hfin);
  scan_pass2<<<dim3(B_ * NP / 256, NCHUNK), 256, 0, stream>>>(Gg, Hs, outbuf);
  gemm_out<<<dim3(D_ / 256, M_ / 256), 512, 0, stream>>>(outbuf, Woutb, x, out);
}